// Round 1
// baseline (255.059 us; speedup 1.0000x reference)
//
#include <hip/hip_runtime.h>

// kernel:  (N=8, K2=25, H=128, W=128) fp32
// low_fea: (N=8, C=256, H=128, W=128) fp32
// out[n,c,y,x] = low_fea[n,c,y,x] * S[n,y,x]
// S[n,y,x]  = sum_{a,b in [0,5)} kernel[n, a*5+b, y+2-a, x+2-b]  (0 outside bounds)
#define NN 8
#define CC 256
#define HH 128
#define WW 128
#define KK 5
#define PAD 2

typedef float f4 __attribute__((ext_vector_type(4)));

// ---------- Kernel A: S[n,y,x] -> d_ws (8*128*128 floats = 512 KB) ----------
// One block (128 threads) per (n,y) row; lane = x. Reads kernel tensor once
// (5x vertical row overlap absorbed by L2).
__global__ __launch_bounds__(128) void s_compute_kernel(
    const float* __restrict__ kern, float* __restrict__ S)
{
    const int blk = blockIdx.x;        // 0 .. N*H-1
    const int n   = blk >> 7;
    const int y   = blk & (HH - 1);
    const int x   = threadIdx.x;

    float s = 0.0f;
    const float* kb = kern + (size_t)n * (KK * KK) * HH * WW;
#pragma unroll
    for (int a = 0; a < KK; ++a) {
        const int yy = y + PAD - a;
        if (yy >= 0 && yy < HH) {
#pragma unroll
            for (int b = 0; b < KK; ++b) {
                const int xx = x + PAD - b;
                if (xx >= 0 && xx < WW) {
                    s += kb[((size_t)(a * KK + b) * HH + yy) * WW + xx];
                }
            }
        }
    }
    S[(size_t)blk * WW + x] = s;
}

// ---------- Kernel B: out = low * S[broadcast] — flat linear streaming ----------
// Total float4 elements: 8*256*128*128/4 = 8388608 = 2^23.
// 2048 blocks x 256 threads, block-stride: thread t handles i = t + it*2^19,
// 16 iterations. Consecutive lanes -> consecutive float4 -> the whole grid
// sweeps the tensor linearly (uniform HBM channel load; no 64KB-stride hot
// channels). S factor recovered from flat index by shifts (dims are pow2):
//   xq = i & 31, y = (i>>5) & 127, n = i >> 20  (C*H*W/4 = 2^20)
#define SCALE_BLOCKS  2048
#define SCALE_THREADS 256
#define SCALE_STRIDE  (SCALE_BLOCKS * SCALE_THREADS)   // 2^19
#define SCALE_ITERS   16                                // 2^23 / 2^19

__global__ __launch_bounds__(SCALE_THREADS) void scale_kernel(
    const float* __restrict__ low,
    const float* __restrict__ S,
    float* __restrict__ out)
{
    const int t = blockIdx.x * SCALE_THREADS + threadIdx.x;   // 0 .. 2^19-1
    const f4* __restrict__ lf4  = (const f4*)low;
    const f4* __restrict__ S4   = (const f4*)S;
    f4*       __restrict__ out4 = (f4*)out;

#pragma unroll
    for (int it = 0; it < SCALE_ITERS; ++it) {
        const int i    = t + it * SCALE_STRIDE;
        const int xq   = i & 31;
        const int y    = (i >> 5) & (HH - 1);
        const int n    = i >> 20;
        const int sidx = ((((n << 7) | y) << 5) | xq);

        f4 v = __builtin_nontemporal_load(lf4 + i);   // zero-reuse: bypass L2 retention
        f4 s = S4[sidx];                              // 512 KB total: L2-resident
        f4 r = v * s;
        __builtin_nontemporal_store(r, out4 + i);     // write-only stream
    }
}

// ---------- Fallback (fused) if ws too small ----------
__global__ __launch_bounds__(256) void fused_scale_kernel(
    const float* __restrict__ kern,
    const float* __restrict__ low,
    float* __restrict__ out)
{
    __shared__ __align__(16) float S[WW];
    const int blk = blockIdx.x;
    const int n   = blk >> 7;
    const int y   = blk & (HH - 1);
    const int tid = threadIdx.x;

    if (tid < WW) {
        const int x = tid;
        float s = 0.0f;
        const float* kb = kern + (size_t)n * (KK * KK) * HH * WW;
#pragma unroll
        for (int a = 0; a < KK; ++a) {
            const int yy = y + PAD - a;
            if (yy >= 0 && yy < HH) {
#pragma unroll
                for (int b = 0; b < KK; ++b) {
                    const int xx = x + PAD - b;
                    if (xx >= 0 && xx < WW) {
                        s += kb[((size_t)(a * KK + b) * HH + yy) * WW + xx];
                    }
                }
            }
        }
        S[x] = s;
    }
    __syncthreads();

    const f4* lf4  = (const f4*)low;
    f4*       out4 = (f4*)out;
    const size_t base4 = (((size_t)n * CC * HH + (size_t)y) * WW) >> 2;
    const int    xq    = tid & 31;
    const f4 s4 = *(const f4*)&S[xq * 4];

#pragma unroll 8
    for (int it = 0; it < 32; ++it) {
        const int    c   = it * 8 + (tid >> 5);
        const size_t idx = base4 + (size_t)c * (HH * WW / 4) + (size_t)xq;
        f4 v = lf4[idx];
        out4[idx] = v * s4;
    }
}

extern "C" void kernel_launch(void* const* d_in, const int* in_sizes, int n_in,
                              void* d_out, int out_size, void* d_ws, size_t ws_size,
                              hipStream_t stream) {
    const float* kern = (const float*)d_in[0];  // (8, 25, 128, 128)
    const float* low  = (const float*)d_in[1];  // (8, 256, 128, 128)
    float* out = (float*)d_out;                 // (8, 256, 128, 128)

    const size_t s_bytes = (size_t)NN * HH * WW * sizeof(float);  // 512 KB

    if (ws_size >= s_bytes) {
        float* S = (float*)d_ws;
        s_compute_kernel<<<dim3(NN * HH), dim3(128), 0, stream>>>(kern, S);
        scale_kernel<<<dim3(SCALE_BLOCKS), dim3(SCALE_THREADS), 0, stream>>>(low, S, out);
    } else {
        fused_scale_kernel<<<dim3(NN * HH), dim3(256), 0, stream>>>(kern, low, out);
    }
}

// Round 2
// 247.258 us; speedup vs baseline: 1.0315x; 1.0315x over previous
//
#include <hip/hip_runtime.h>

// kernel:  (N=8, K2=25, H=128, W=128) fp32
// low_fea: (N=8, C=256, H=128, W=128) fp32
// out[n,c,y,x] = low_fea[n,c,y,x] * S[n,y,x]
// S[n,y,x]  = sum_{a,b in [0,5)} kernel[n, a*5+b, y+2-a, x+2-b]  (0 outside bounds)
//
// Single fused kernel. One block per (n,y) row:
//   phase 1: threads 0..127 compute S[x] into LDS (25 taps, mostly L2-hit)
//   phase 2: all 256 threads stream 256 channels of row y: out = low * S
//
// XCD pinning: the dispatcher round-robins blockIdx.x over 8 XCDs (b & 7).
// Mapping n = b & 7 puts each batch image on exactly one XCD, so kernel[n]
// (25*128*128*4 = 1.64 MB) is L2-resident per XCD and the 5x vertical tap
// overlap is absorbed by L2 instead of re-fetched from HBM.
// Traffic: read 134 MB low + ~13 MB kernel, write 134 MB out  => ~45 us at 6.3 TB/s.
#define NN 8
#define CC 256
#define HH 128
#define WW 128
#define KK 5
#define PAD 2

typedef float f4 __attribute__((ext_vector_type(4)));

__global__ __launch_bounds__(256) void fused_kernel(
    const float* __restrict__ kern,
    const float* __restrict__ low,
    float* __restrict__ out)
{
    __shared__ __align__(16) float S[WW];

    const int n   = blockIdx.x & (NN - 1);   // XCD-pinned batch index
    const int y   = blockIdx.x >> 3;         // 0..127
    const int tid = threadIdx.x;

    // ---- phase 1: S row into LDS ----
    if (tid < WW) {
        const int x = tid;
        float s = 0.0f;
        const float* kb = kern + (size_t)n * (KK * KK * HH * WW);
#pragma unroll
        for (int a = 0; a < KK; ++a) {
            const int yy = y + PAD - a;
            if (yy >= 0 && yy < HH) {
#pragma unroll
                for (int b = 0; b < KK; ++b) {
                    const int xx = x + PAD - b;
                    if (xx >= 0 && xx < WW) {
                        s += kb[((a * KK + b) * HH + yy) * WW + xx];
                    }
                }
            }
        }
        S[x] = s;
    }
    __syncthreads();

    // ---- phase 2: stream 256 channels of row (n,y) ----
    const int xq = tid & 31;        // float4 index within the row (W/4 = 32)
    const int c0 = tid >> 5;        // 0..7
    const f4 s4 = *(const f4*)&S[xq * 4];

    const f4* __restrict__ lf4 = (const f4*)(low + ((size_t)n * CC * HH + y) * WW);
    f4* __restrict__       o4  = (f4*)      (out + ((size_t)n * CC * HH + y) * WW);

#pragma unroll 8
    for (int it = 0; it < 32; ++it) {
        const int    c   = c0 + it * 8;
        const size_t idx = (size_t)c * (HH * WW / 4) + xq;   // channel stride 4096 f4
        f4 v = __builtin_nontemporal_load(lf4 + idx);        // zero-reuse stream
        __builtin_nontemporal_store(v * s4, o4 + idx);       // write-only stream
    }
}

extern "C" void kernel_launch(void* const* d_in, const int* in_sizes, int n_in,
                              void* d_out, int out_size, void* d_ws, size_t ws_size,
                              hipStream_t stream) {
    const float* kern = (const float*)d_in[0];  // (8, 25, 128, 128)
    const float* low  = (const float*)d_in[1];  // (8, 256, 128, 128)
    float* out = (float*)d_out;                 // (8, 256, 128, 128)
    (void)d_ws; (void)ws_size;

    fused_kernel<<<dim3(NN * HH), dim3(256), 0, stream>>>(kern, low, out);
}

// Round 3
// 244.176 us; speedup vs baseline: 1.0446x; 1.0126x over previous
//
#include <hip/hip_runtime.h>

// kernel:  (N=8, K2=25, H=128, W=128) fp32
// low_fea: (N=8, C=256, H=128, W=128) fp32
// out[n,c,y,x] = low_fea[n,c,y,x] * S[n,y,x]
// S[n,y,x]  = sum_{a,b in [0,5)} kernel[n, a*5+b, y+2-a, x+2-b]  (0 outside bounds)
//
// Fused, one dispatch. Block = (n, y, channel-half). 2048 blocks -> 8 blocks/CU:
//   phase 1: ALL 256 threads compute S[x] partials (taps a<3 on half 0, a>=3 on
//            half 1) into LDS; combined at read time. No idle half-block.
//   phase 2: stream 128 channels of row (n,y): out = low * S, float4 NT.
//
// XCD pinning: dispatcher round-robins blockIdx.x over 8 XCDs (b & 7); n = b & 7
// keeps kernel[n] (1.64 MB) resident in one XCD's 4 MiB L2, so the 5x vertical
// tap overlap and the 2x chunk recompute are L2 hits, not HBM re-fetch.
// HBM traffic: 134 MB low + ~13 MB kernel reads, 134 MB writes -> ~45 us @ 6.3 TB/s.
#define NN 8
#define CC 256
#define HH 128
#define WW 128
#define KK 5
#define PAD 2

typedef float f4 __attribute__((ext_vector_type(4)));

__global__ __launch_bounds__(256) void fused_kernel(
    const float* __restrict__ kern,
    const float* __restrict__ low,
    float* __restrict__ out)
{
    __shared__ __align__(16) float Sp[2][WW];

    const int b     = blockIdx.x;
    const int n     = b & (NN - 1);          // XCD-pinned batch index
    const int rest  = b >> 3;                // 0..255
    const int y     = rest & (HH - 1);       // 0..127
    const int chunk = rest >> 7;             // 0..1 (channel half)
    const int tid   = threadIdx.x;

    // ---- phase 1: S row partials, all 256 threads ----
    {
        const int half = tid >> 7;           // 0: taps a=0..2, 1: taps a=3..4
        const int x    = tid & (WW - 1);
        const int a_lo = half ? 3 : 0;
        const int a_hi = half ? KK : 3;
        float s = 0.0f;
        const float* kb = kern + (size_t)n * (KK * KK * HH * WW);
        for (int a = a_lo; a < a_hi; ++a) {
            const int yy = y + PAD - a;
            if (yy >= 0 && yy < HH) {
#pragma unroll
                for (int bb = 0; bb < KK; ++bb) {
                    const int xx = x + PAD - bb;
                    if (xx >= 0 && xx < WW) {
                        s += kb[((a * KK + bb) * HH + yy) * WW + xx];
                    }
                }
            }
        }
        Sp[half][x] = s;
    }
    __syncthreads();

    // ---- phase 2: stream 128 channels of row (n,y) ----
    const int xq = tid & 31;                 // float4 index in row (W/4 = 32)
    const int c0 = (chunk << 7) + (tid >> 5);
    const f4 s4 = *(const f4*)&Sp[0][xq * 4] + *(const f4*)&Sp[1][xq * 4];

    const f4* __restrict__ lf4 = (const f4*)(low + ((size_t)n * CC * HH + y) * WW);
    f4* __restrict__       o4  = (f4*)      (out + ((size_t)n * CC * HH + y) * WW);

#pragma unroll 8
    for (int it = 0; it < 16; ++it) {
        const int    c   = c0 + it * 8;
        const size_t idx = (size_t)c * (HH * WW / 4) + xq;   // channel stride 4096 f4
        f4 v = __builtin_nontemporal_load(lf4 + idx);        // zero-reuse stream
        __builtin_nontemporal_store(v * s4, o4 + idx);       // write-only stream
    }
}

extern "C" void kernel_launch(void* const* d_in, const int* in_sizes, int n_in,
                              void* d_out, int out_size, void* d_ws, size_t ws_size,
                              hipStream_t stream) {
    const float* kern = (const float*)d_in[0];  // (8, 25, 128, 128)
    const float* low  = (const float*)d_in[1];  // (8, 256, 128, 128)
    float* out = (float*)d_out;                 // (8, 256, 128, 128)
    (void)d_ws; (void)ws_size;

    fused_kernel<<<dim3(NN * HH * 2), dim3(256), 0, stream>>>(kern, low, out);
}